// Round 2
// baseline (120.196 us; speedup 1.0000x reference)
//
#include <hip/hip_runtime.h>
#include <hip/hip_bf16.h>

// Problem constants
#define BB 32
#define SS 512
#define LL 8
#define HH 1024
#define DD 64

typedef __attribute__((ext_vector_type(8))) short bf16x8;
typedef __attribute__((ext_vector_type(8))) unsigned short u16x8;
typedef __attribute__((ext_vector_type(4))) float f32x4;

__device__ __forceinline__ unsigned short f2bf(float x) {
    unsigned int u = __float_as_uint(x);
    u += 0x7FFFu + ((u >> 16) & 1u);   // round-to-nearest-even
    return (unsigned short)(u >> 16);
}

// ---------------------------------------------------------------------------
// Kernel 0: fragment-major B pack (unchanged).
// Bpack[(cg*32 + c)*64 + ln] (16 B per entry) = the b-fragment lane `ln` of
// col-group `cg` needs at K-chunk `c`:
//   n = cg*16 + (ln&15), k = (ln>>4)*8 + c*32 + j  (j = 0..7)
//   value = bf16(term_weight[k] * W1[k][n])
// ---------------------------------------------------------------------------
__global__ __launch_bounds__(256) void k_prep(const float* __restrict__ W1,
                                              const float* __restrict__ tw,
                                              unsigned short* __restrict__ Bpack) {
    int g = blockIdx.x * 256 + threadIdx.x;   // g < 4*32*64 = 8192
    int ln = g & 63;
    int c  = (g >> 6) & 31;
    int cg = g >> 11;
    int n  = cg * 16 + (ln & 15);
    int hb = (ln >> 4) * 8 + c * 32;
    u16x8 pk;
#pragma unroll
    for (int j = 0; j < 8; j++) {
        float val = tw[hb + j] * W1[(hb + j) * DD + n];
        pk[j] = f2bf(val);
    }
    *(u16x8*)(Bpack + (size_t)g * 8) = pk;
}

// ---------------------------------------------------------------------------
// Kernel 1: direct-from-global fragment streaming, no A staging.
//   - 256 thr/block = 4 waves, block owns 16 rows; each wave owns a K-quarter
//     (K=256 -> 8 chunks of 32). 1024 blocks, ~4 blocks/CU, 16 waves/CU.
//   - Per chunk: lane loads hidden[row0+(ln&15)][kq*256 + cc*32 + quad*8 .. +8]
//     as 2x float4 (4 quads x 16 rows = 16 x 128 B coalesced segments),
//     converts to bf16x8 in registers -> 4 MFMAs (one per col-group).
//     v = h . Ws fused on the same registers.
//   - No barrier between load and compute; HBM / convert / L2-B / MFMA all
//     overlap across 4 independent blocks per CU. LDS only for the 4-way
//     K-split reduction (16.9 KB vs 132 KB before -> occupancy VGPR-bound).
// ---------------------------------------------------------------------------
__global__ __launch_bounds__(256, 4) void k_main(
        const float* __restrict__ hidden,
        const unsigned short* __restrict__ Bpack,
        const float* __restrict__ b1,
        const float* __restrict__ W2,
        const float* __restrict__ b2,
        const float* __restrict__ Ws,
        float* __restrict__ e1,
        float* __restrict__ vout) {
    __shared__ float red[4][16][65];   // [kq][row][col], pad 65: quads hit distinct banks
    __shared__ float vred[4][16];

    const int tid  = threadIdx.x;
    const int wv   = tid >> 6;        // K-quarter 0..3
    const int ln   = tid & 63;
    const int ln15 = ln & 15;
    const int quad = ln >> 4;
    const int row0 = blockIdx.x * 16;

    const float* aptr = hidden + (size_t)(row0 + ln15) * HH + wv * 256 + quad * 8;
    const float* wsp  = Ws + wv * 256 + quad * 8;
    const unsigned short* bptr = Bpack + ((size_t)(wv * 8) * 64 + ln) * 8;

    f32x4 acc[4];
#pragma unroll
    for (int cg = 0; cg < 4; cg++) acc[cg] = (f32x4){0.f, 0.f, 0.f, 0.f};
    float vp = 0.f;

#pragma unroll
    for (int cc = 0; cc < 8; cc++) {
        float4 h0 = *(const float4*)(aptr + cc * 32);
        float4 h1 = *(const float4*)(aptr + cc * 32 + 4);
        float4 w0 = *(const float4*)(wsp + cc * 32);      // uniform per quad: L1 broadcast
        float4 w1 = *(const float4*)(wsp + cc * 32 + 4);
        vp += h0.x * w0.x + h0.y * w0.y + h0.z * w0.z + h0.w * w0.w
            + h1.x * w1.x + h1.y * w1.y + h1.z * w1.z + h1.w * w1.w;
        bf16x8 af;
        af[0] = (short)f2bf(h0.x); af[1] = (short)f2bf(h0.y);
        af[2] = (short)f2bf(h0.z); af[3] = (short)f2bf(h0.w);
        af[4] = (short)f2bf(h1.x); af[5] = (short)f2bf(h1.y);
        af[6] = (short)f2bf(h1.z); af[7] = (short)f2bf(h1.w);
#pragma unroll
        for (int cg = 0; cg < 4; cg++) {
            // b-fragment for global chunk c = wv*8 + cc, col-group cg
            bf16x8 bfrag = *(const bf16x8*)(bptr + (cg * 32 + cc) * 512);
            acc[cg] = __builtin_amdgcn_mfma_f32_16x16x32_bf16(af, bfrag, acc[cg], 0, 0, 0);
        }
    }

    // v partial for this K-quarter: sum the 4 quads (same row ln15)
    vp += __shfl_xor(vp, 16);
    vp += __shfl_xor(vp, 32);
    if (quad == 0) vred[wv][ln15] = vp;

    // stash partial C tile: D layout row = quad*4+reg, col = cg*16+ln15
#pragma unroll
    for (int cg = 0; cg < 4; cg++) {
#pragma unroll
        for (int reg = 0; reg < 4; reg++) {
            red[wv][quad * 4 + reg][cg * 16 + ln15] = acc[cg][reg];
        }
    }
    __syncthreads();

    // epilogue: sum K-quarters, relu(x+b1)*W2, reduce 64 cols -> e1
    {
        const int rl = tid >> 4;          // row 0..15
        const int c0 = (tid & 15) * 4;    // 4 cols per thread
        float ep = 0.f;
#pragma unroll
        for (int j = 0; j < 4; j++) {
            int c = c0 + j;
            float x = red[0][rl][c] + red[1][rl][c] + red[2][rl][c] + red[3][rl][c];
            ep += fmaxf(x + b1[c], 0.f) * W2[c];
        }
        ep += __shfl_xor(ep, 1);
        ep += __shfl_xor(ep, 2);
        ep += __shfl_xor(ep, 4);
        ep += __shfl_xor(ep, 8);
        if ((tid & 15) == 0) e1[row0 + rl] = ep + b2[0];
        if (tid < 16) vout[row0 + tid] = vred[0][tid] + vred[1][tid] + vred[2][tid] + vred[3][tid];
    }
}

// ---------------------------------------------------------------------------
// Kernel 2: span scoring (unchanged). One thread per (b, s), online softmax.
// ---------------------------------------------------------------------------
__global__ __launch_bounds__(256) void k_span(
        const float* __restrict__ e1,
        const float* __restrict__ v,
        const int* __restrict__ seq_lengths,
        const float* __restrict__ bs,
        float* __restrict__ out) {
    int i = blockIdx.x * 256 + threadIdx.x;   // i < B*S
    int b = i >> 9;
    int s = i & (SS - 1);
    int sl = seq_lengths[b];
    float res[LL];

    if (s >= sl) {
#pragma unroll
        for (int l = 0; l < LL; l++) res[l] = 0.f;
    } else {
        const float bsv = bs[0];
        float e[LL], vv[LL];
        int base = b << 9;
#pragma unroll
        for (int j = 0; j < LL; j++) {
            int pos = s + j; if (pos > SS - 1) pos = SS - 1;
            e[j]  = e1[base + pos];
            vv[j] = v[base + pos];
        }
        // j = 0 is always valid when s < sl
        float M = e[0], Z = 1.f, W = vv[0];
        res[0] = W / Z + bsv;
#pragma unroll
        for (int l = 1; l < LL; l++) {
            if (s + l < sl) {
                float el = e[l];
                if (el > M) {
                    float c = __expf(M - el);
                    Z = Z * c + 1.f;
                    W = W * c + vv[l];
                    M = el;
                } else {
                    float p = __expf(el - M);
                    Z += p;
                    W += p * vv[l];
                }
            }
            res[l] = W / Z + bsv;
        }
    }
    float4* o = (float4*)(out + (size_t)i * LL);
    o[0] = make_float4(res[0], res[1], res[2], res[3]);
    o[1] = make_float4(res[4], res[5], res[6], res[7]);
}

extern "C" void kernel_launch(void* const* d_in, const int* in_sizes, int n_in,
                              void* d_out, int out_size, void* d_ws, size_t ws_size,
                              hipStream_t stream) {
    const float* hidden = (const float*)d_in[0];
    const int*   seqlen = (const int*)d_in[1];
    const float* tw     = (const float*)d_in[2];
    const float* W1     = (const float*)d_in[3];
    const float* b1     = (const float*)d_in[4];
    const float* W2     = (const float*)d_in[5];
    const float* b2     = (const float*)d_in[6];
    const float* Ws     = (const float*)d_in[7];
    const float* bs     = (const float*)d_in[8];
    float* out = (float*)d_out;

    // workspace layout
    unsigned short* Bpack = (unsigned short*)d_ws;                      // 131072 B
    float* e1 = (float*)((char*)d_ws + 131072);                         // 65536 B
    float* vv = (float*)((char*)d_ws + 131072 + 65536);                 // 65536 B

    // kernel 0: fold term_weight into W1, pack fragment-major, bf16
    k_prep<<<32, 256, 0, stream>>>(W1, tw, Bpack);

    // kernel 1: per-position e1 / v — direct-stream, 16 rows/block
    k_main<<<(BB * SS) / 16, 256, 0, stream>>>(hidden, Bpack, b1, W2, b2, Ws, e1, vv);

    // kernel 2: span scores
    k_span<<<(BB * SS) / 256, 256, 0, stream>>>(e1, vv, seqlen, bs, out);
}

// Round 3
// 114.087 us; speedup vs baseline: 1.0535x; 1.0535x over previous
//
#include <hip/hip_runtime.h>
#include <hip/hip_bf16.h>

// Problem constants
#define BB 32
#define SS 512
#define LL 8
#define HH 1024
#define DD 64

#define BM 32        // rows per block (512 thr, 66.5 KB LDS -> 2 blocks/CU so one
                     // block's MFMA phase overlaps the other's HBM stage phase)
#define ROWSTR 1032  // LDS row stride in bf16 elems (2064 B: 16B-aligned; phase-2 read
                     // pattern is uniform 8 lanes per 4-bank group = b128 minimum, conflict-free)

typedef __attribute__((ext_vector_type(8))) short bf16x8;
typedef __attribute__((ext_vector_type(8))) unsigned short u16x8;
typedef __attribute__((ext_vector_type(4))) float f32x4;

__device__ __forceinline__ unsigned short f2bf(float x) {
    unsigned int u = __float_as_uint(x);
    u += 0x7FFFu + ((u >> 16) & 1u);   // round-to-nearest-even
    return (unsigned short)(u >> 16);
}

// ---------------------------------------------------------------------------
// Kernel 0: fragment-major B pack.
// Bpack[(cg*32 + c)*64 + ln] (16 B per entry) = the b-fragment lane `ln` of
// col-group `cg` needs at K-chunk `c` in k_main's MFMA loop:
//   n = cg*16 + (ln&15), k = (ln>>4)*8 + c*32 + j  (j = 0..7)
//   value = bf16(term_weight[k] * W1[k][n])
// ---------------------------------------------------------------------------
__global__ __launch_bounds__(256) void k_prep(const float* __restrict__ W1,
                                              const float* __restrict__ tw,
                                              unsigned short* __restrict__ Bpack) {
    int g = blockIdx.x * 256 + threadIdx.x;   // g < 4*32*64 = 8192
    int ln = g & 63;
    int c  = (g >> 6) & 31;
    int cg = g >> 11;
    int n  = cg * 16 + (ln & 15);
    int hb = (ln >> 4) * 8 + c * 32;
    u16x8 pk;
#pragma unroll
    for (int j = 0; j < 8; j++) {
        float val = tw[hb + j] * W1[(hb + j) * DD + n];
        pk[j] = f2bf(val);
    }
    *(u16x8*)(Bpack + (size_t)g * 8) = pk;
}

// ---------------------------------------------------------------------------
// Kernel 1: per-position e1 and v. BM=32 rows/block, 512 thr (8 waves as
// 2 row-groups x 4 col-groups of 16x16 MFMA tiles).
//   phase 1: hoist ALL 16 float4 A-loads into registers (16 outstanding
//            loads/thread), then convert->LDS + fused v = h @ Ws.
//   phase 2: barrier-free MFMA loop; B fragments from packed global Bpack
//            (L2-resident) with explicit 4-deep rolling prefetch.
// LDS 64.5 KB + 0.5 KB -> 2 blocks/CU; co-resident blocks run the two phases
// out of lockstep so HBM stays busy during this block's MFMA phase.
// ---------------------------------------------------------------------------
__global__ __launch_bounds__(512, 4) void k_main(
        const float* __restrict__ hidden,
        const unsigned short* __restrict__ Bpack,
        const float* __restrict__ b1,
        const float* __restrict__ W2,
        const float* __restrict__ b2,
        const float* __restrict__ Ws,
        float* __restrict__ e1,
        float* __restrict__ vout) {
    __shared__ unsigned short Alds[BM * ROWSTR];   // 66048 B
    __shared__ float eplds[4][BM];                 // 512 B

    const int tid = threadIdx.x;
    const int row0 = blockIdx.x * BM;

    // ---- phase 1: deep-pipelined A stage + fused v partial ----
    {
        const int r  = tid >> 4;          // 0..31: which row this thread stages
        const int co = (tid & 15) * 4;    // float offset within 64-float segment
        const float* arow = hidden + (size_t)(row0 + r) * HH + co;
        float4 h[16];
#pragma unroll
        for (int i = 0; i < 16; i++) h[i] = *(const float4*)(arow + i * 64);

        float vp = 0.f;
#pragma unroll
        for (int i = 0; i < 16; i++) {
            float4 w4 = *(const float4*)(Ws + co + i * 64);
            vp += h[i].x * w4.x + h[i].y * w4.y + h[i].z * w4.z + h[i].w * w4.w;
            ushort4 a4;
            a4.x = f2bf(h[i].x); a4.y = f2bf(h[i].y);
            a4.z = f2bf(h[i].z); a4.w = f2bf(h[i].w);
            *(ushort4*)&Alds[r * ROWSTR + co + i * 64] = a4;
        }
        // v reduction across the 16 threads sharing a row
        vp += __shfl_xor(vp, 1);
        vp += __shfl_xor(vp, 2);
        vp += __shfl_xor(vp, 4);
        vp += __shfl_xor(vp, 8);
        if ((tid & 15) == 0) vout[row0 + r] = vp;
    }
    __syncthreads();

    // ---- phase 2: barrier-free MFMA loop, 4-deep B prefetch ----
    const int wv   = tid >> 6;     // wave 0..7
    const int rg   = wv >> 2;      // row-group: rows 16*rg .. 16*rg+15 (rg in 0..1)
    const int cg   = wv & 3;       // col-group: cols 16*cg .. 16*cg+15
    const int ln   = tid & 63;
    const int ln15 = ln & 15;
    const int quad = ln >> 4;

    const unsigned short* bptr = Bpack + ((size_t)(cg * 32) * 64 + ln) * 8;
    const unsigned short* aptr = &Alds[(rg * 16 + ln15) * ROWSTR + quad * 8];

    bf16x8 bf[4];
#pragma unroll
    for (int i = 0; i < 4; i++) bf[i] = *(const bf16x8*)(bptr + i * 512);

    f32x4 acc = {0.f, 0.f, 0.f, 0.f};
#pragma unroll
    for (int c = 0; c < 32; c++) {
        bf16x8 bcur = bf[c & 3];
        if (c + 4 < 32) bf[c & 3] = *(const bf16x8*)(bptr + (c + 4) * 512);
        bf16x8 afrag = *(const bf16x8*)(aptr + c * 32);
        acc = __builtin_amdgcn_mfma_f32_16x16x32_bf16(afrag, bcur, acc, 0, 0, 0);
    }

    // ---- epilogue: relu(x + b1) * W2, reduce over this wave's 16 cols ----
    const int col = cg * 16 + ln15;
    const float b1c = b1[col];
    const float w2c = W2[col];
    float ep[4];
#pragma unroll
    for (int reg = 0; reg < 4; reg++) {
        ep[reg] = fmaxf(acc[reg] + b1c, 0.f) * w2c;
    }
#pragma unroll
    for (int off = 1; off < 16; off <<= 1) {
#pragma unroll
        for (int i = 0; i < 4; i++) ep[i] += __shfl_xor(ep[i], off);
    }
    if (ln15 == 0) {
#pragma unroll
        for (int reg = 0; reg < 4; reg++)
            eplds[cg][rg * 16 + quad * 4 + reg] = ep[reg];
    }
    __syncthreads();
    if (tid < BM) {
        e1[row0 + tid] = b2[0] + eplds[0][tid] + eplds[1][tid] + eplds[2][tid] + eplds[3][tid];
    }
}

// ---------------------------------------------------------------------------
// Kernel 2: span scoring. One thread per (b, s). Online softmax over j<=l.
// ---------------------------------------------------------------------------
__global__ __launch_bounds__(256) void k_span(
        const float* __restrict__ e1,
        const float* __restrict__ v,
        const int* __restrict__ seq_lengths,
        const float* __restrict__ bs,
        float* __restrict__ out) {
    int i = blockIdx.x * 256 + threadIdx.x;   // i < B*S
    int b = i >> 9;
    int s = i & (SS - 1);
    int sl = seq_lengths[b];
    float res[LL];

    if (s >= sl) {
#pragma unroll
        for (int l = 0; l < LL; l++) res[l] = 0.f;
    } else {
        const float bsv = bs[0];
        float e[LL], vv[LL];
        int base = b << 9;
#pragma unroll
        for (int j = 0; j < LL; j++) {
            int pos = s + j; if (pos > SS - 1) pos = SS - 1;
            e[j]  = e1[base + pos];
            vv[j] = v[base + pos];
        }
        // j = 0 is always valid when s < sl
        float M = e[0], Z = 1.f, W = vv[0];
        res[0] = W / Z + bsv;
#pragma unroll
        for (int l = 1; l < LL; l++) {
            if (s + l < sl) {
                float el = e[l];
                if (el > M) {
                    float c = __expf(M - el);
                    Z = Z * c + 1.f;
                    W = W * c + vv[l];
                    M = el;
                } else {
                    float p = __expf(el - M);
                    Z += p;
                    W += p * vv[l];
                }
            }
            res[l] = W / Z + bsv;
        }
    }
    float4* o = (float4*)(out + (size_t)i * LL);
    o[0] = make_float4(res[0], res[1], res[2], res[3]);
    o[1] = make_float4(res[4], res[5], res[6], res[7]);
}

extern "C" void kernel_launch(void* const* d_in, const int* in_sizes, int n_in,
                              void* d_out, int out_size, void* d_ws, size_t ws_size,
                              hipStream_t stream) {
    const float* hidden = (const float*)d_in[0];
    const int*   seqlen = (const int*)d_in[1];
    const float* tw     = (const float*)d_in[2];
    const float* W1     = (const float*)d_in[3];
    const float* b1     = (const float*)d_in[4];
    const float* W2     = (const float*)d_in[5];
    const float* b2     = (const float*)d_in[6];
    const float* Ws     = (const float*)d_in[7];
    const float* bs     = (const float*)d_in[8];
    float* out = (float*)d_out;

    // workspace layout
    unsigned short* Bpack = (unsigned short*)d_ws;                      // 131072 B
    float* e1 = (float*)((char*)d_ws + 131072);                         // 65536 B
    float* vv = (float*)((char*)d_ws + 131072 + 65536);                 // 65536 B

    // kernel 0: fold term_weight into W1, pack fragment-major, bf16
    k_prep<<<32, 256, 0, stream>>>(W1, tw, Bpack);

    // kernel 1: per-position e1 / v — BM=32, 2 blocks/CU for phase overlap
    k_main<<<(BB * SS) / BM, 512, 0, stream>>>(hidden, Bpack, b1, W2, b2, Ws, e1, vv);

    // kernel 2: span scores
    k_span<<<(BB * SS) / 256, 256, 0, stream>>>(e1, vv, seqlen, bs, out);
}